// Round 15
// baseline (319.649 us; speedup 1.0000x reference)
//
#include <hip/hip_runtime.h>
#include <stdint.h>

// BiMultiHeadAttention (GLIP bi-attention), MI355X bf16 MFMA pipeline.
// B=32 VN=576 LN=128 E=1024 H=16 D=64, V_DIM=1024 L_DIM=768, SCALE=0.25.

typedef unsigned short bfu;   // bf16 storage
typedef __attribute__((ext_vector_type(4))) float f32x4;
typedef __attribute__((ext_vector_type(8))) short short8;
typedef __attribute__((ext_vector_type(4))) unsigned short u16x4;

#define MFMA16(a,b,c) __builtin_amdgcn_mfma_f32_16x16x32_bf16((a),(b),(c),0,0,0)
#define SCALE_QK 0.25f

__device__ __forceinline__ unsigned short f2bf(float x) {
  unsigned int u = __float_as_uint(x);
  u += 0x7fffu + ((u >> 16) & 1u);   // round-to-nearest-even
  return (unsigned short)(u >> 16);
}

__device__ __forceinline__ void gload_lds16(const void* g, void* l) {
  __builtin_amdgcn_global_load_lds(
      reinterpret_cast<__attribute__((address_space(1))) void*>(
          reinterpret_cast<uintptr_t>(g)),
      reinterpret_cast<__attribute__((address_space(3))) void*>(
          (uint32_t)reinterpret_cast<uintptr_t>(l)),
      16, 0, 0);
}

// ---------------------------------------------------------------- converts
__global__ void cvt_f32_bf16(const float* __restrict__ x, bfu* __restrict__ y, int n4) {
  for (int i = blockIdx.x * blockDim.x + threadIdx.x; i < n4; i += gridDim.x * blockDim.x) {
    const float4 f = *reinterpret_cast<const float4*>(x + (size_t)i * 4);
    u16x4 o;
    o[0] = f2bf(f.x); o[1] = f2bf(f.y); o[2] = f2bf(f.z); o[3] = f2bf(f.w);
    *reinterpret_cast<u16x4*>(y + (size_t)i * 4) = o;
  }
}

struct CvtArgs {
  const float* src[7];
  bfu* dst[7];
  int n4[7];
};

__global__ void cvt_multi(CvtArgs a) {
  const int s = blockIdx.y;
  const float* __restrict__ x = a.src[s];
  bfu* __restrict__ y = a.dst[s];
  const int n4 = a.n4[s];
  for (int i = blockIdx.x * blockDim.x + threadIdx.x; i < n4; i += gridDim.x * blockDim.x) {
    const float4 f = *reinterpret_cast<const float4*>(x + (size_t)i * 4);
    u16x4 o;
    o[0] = f2bf(f.x); o[1] = f2bf(f.y); o[2] = f2bf(f.z); o[3] = f2bf(f.w);
    *reinterpret_cast<u16x4*>(y + (size_t)i * 4) = o;
  }
}

// bias concat: one dispatch replaces 4 d2d memcpies
__global__ void bias_concat(const float* __restrict__ a, const float* __restrict__ b,
                            const float* __restrict__ c2, const float* __restrict__ d,
                            float* __restrict__ qv, float* __restrict__ kl) {
  const int i = threadIdx.x * 4;
  const float4* s;
  float* o;
  switch (blockIdx.x) {
    case 0: s = (const float4*)a;  o = qv;        break;
    case 1: s = (const float4*)b;  o = qv + 1024; break;
    case 2: s = (const float4*)c2; o = kl;        break;
    default: s = (const float4*)d; o = kl + 1024; break;
  }
  *reinterpret_cast<float4*>(o + i) = s[threadIdx.x];
}

// ---------------------------------------------------------------- GEMM 128-tile (m97 structure) — R5 version
__global__ __launch_bounds__(256) void gemm_bt(
    const bfu* __restrict__ A, const bfu* __restrict__ W, const float* __restrict__ bias,
    bfu* __restrict__ Cb, float* __restrict__ Cf, bfu* __restrict__ Ct, int R, int colsplit,
    int ldc, int M, int N, int K, int nbn)
{
  __shared__ bfu As[128 * 32];
  __shared__ bfu Bs[128 * 32];
  const int nbm = M >> 7;
  const int bid = blockIdx.x;
  int bm, bn;
  if ((nbm & 7) == 0) {             // bijective XCD-aware swizzle
    const int xcd = bid & 7, j = bid >> 3;
    const int jm = j / nbn;
    bm = xcd * (nbm >> 3) + jm;
    bn = j - jm * nbn;
  } else { bm = bid / nbn; bn = bid - (bid / nbn) * nbn; }

  const int t = threadIdx.x, l = t & 63, w = t >> 6;
  const int g = l >> 4, c = l & 15;
  const int wr = (w >> 1) * 64, wc = (w & 1) * 64;

  f32x4 zero = {0.f, 0.f, 0.f, 0.f};
  f32x4 acc[4][4];
  for (int m = 0; m < 4; ++m)
    for (int n = 0; n < 4; ++n) acc[m][n] = zero;

  const int rowA = l >> 2;
  const int kb   = (l & 3) * 16;

  for (int k0 = 0; k0 < K; k0 += 32) {
#pragma unroll
    for (int i = 0; i < 2; ++i) {
      int chunk = w * 2 + i;
      int r = chunk * 16 + rowA;
      const char* ga = (const char*)(A + (size_t)(bm * 128 + r) * K + k0) + kb;
      const char* gb = (const char*)(W + (size_t)(bn * 128 + r) * K + k0) + kb;
      gload_lds16(ga, (char*)As + chunk * 1024);
      gload_lds16(gb, (char*)Bs + chunk * 1024);
    }
    __syncthreads();
    short8 a[4], bf[4];
#pragma unroll
    for (int m = 0; m < 4; ++m)
      a[m] = *reinterpret_cast<const short8*>(&As[(wr + m * 16 + c) * 32 + g * 8]);
#pragma unroll
    for (int n = 0; n < 4; ++n)
      bf[n] = *reinterpret_cast<const short8*>(&Bs[(wc + n * 16 + c) * 32 + g * 8]);
#pragma unroll
    for (int m = 0; m < 4; ++m)
#pragma unroll
      for (int n = 0; n < 4; ++n)
        acc[m][n] = MFMA16(a[m], bf[n], acc[m][n]);
    __syncthreads();
  }

#pragma unroll
  for (int n = 0; n < 4; ++n) {
    const int col = bn * 128 + wc + n * 16 + c;
    const float bs = bias[col];
    if (col >= colsplit) {
      const int colp = col - colsplit;
      const int hh = colp >> 6, dd = colp & 63;
#pragma unroll
      for (int m = 0; m < 4; ++m) {
        const int row0 = bm * 128 + wr + m * 16 + g * 4;
        const int bb = row0 / R, q0 = row0 - bb * R;
        u16x4 pk;
#pragma unroll
        for (int r = 0; r < 4; ++r) pk[r] = f2bf(acc[m][n][r] + bs);
        *reinterpret_cast<u16x4*>(Ct + ((size_t)(bb * 16 + hh) * 64 + dd) * R + q0) = pk;
      }
    } else {
#pragma unroll
      for (int m = 0; m < 4; ++m) {
        const int row0 = bm * 128 + wr + m * 16 + g * 4;
#pragma unroll
        for (int r = 0; r < 4; ++r) {
          float val = acc[m][n][r] + bs;
          size_t idx = (size_t)(row0 + r) * ldc + col;
          if (Cf) Cf[idx] = val;
          else    Cb[idx] = f2bf(val);
        }
      }
    }
  }
}

// ---------------------------------------------------------------- GEMM 288x256-tile, B direct from L2 (R15)
// BM=288, BN=256, BK=64, 512 thr (8 waves: wr=w>>2, wc=w&3).
// A: LDS double-buffer (80 KB total -> 2 blocks/CU), 128B-row XOR swizzle, 5 stages/tile.
// B: NO LDS -- fragments loaded directly from global (W panel is L2-resident), 8 loads/tile
//    issued at p3 of the previous tile into bD registers (1:1 replacing the old bF).
// One counted wait per tile: vmcnt(8) at p3 (drains the 5 A-stages issued 3 phases back,
// leaves the 8 B register-loads in flight; compiler guards their register uses).
template<int RT>
__global__ __launch_bounds__(512, 2) void gemm288(
    const bfu* __restrict__ A, const bfu* __restrict__ W, const float* __restrict__ bias,
    bfu* __restrict__ Cb, float* __restrict__ Cf, bfu* __restrict__ Ct, int colsplit,
    int ldc, int M, int N, int K, int nbn)
{
  __shared__ bfu lds[2 * 20480];      // 81920 B: A double-buffer only (320x64 rows, 288-319 pad)

  const int tid = threadIdx.x;
  const int w = tid >> 6, lane = tid & 63;
  const int g = lane >> 4, c = lane & 15;
  const int wr = w >> 2, wc = w & 3;
  const int rb0 = wr ? 208 : 0;       // mh0 row base (5 tiles)
  const int rb1 = wr ? 144 : 80;      // mh1 row base (4 tiles)

  const int nbm = M / 288;
  int bm, bn;
  { const int xcd = blockIdx.x & 7, j = blockIdx.x >> 3;
    const int jm = j / nbn; bm = xcd * (nbm >> 3) + jm; bn = j - jm * nbn; }

  const int nt = K >> 6;

  const int srow8 = lane >> 3;                     // 0..7
  const int sslot = lane & 7;
  const int swzE  = ((sslot * 16) ^ (srow8 << 4)) >> 1;   // pre-swizzled elem offset
  const bfu* srcA = A + (size_t)(bm * 288 + 8 * w + srow8) * K + swzE;

#define AB(cur) (lds + (cur) * 20480)
#define STAGE_A(cur, j, k0) gload_lds16(srcA + (size_t)(64 * (j)) * K + (k0), \
    (void*)(AB(cur) + (64 * (j) + 8 * w) * 64))

  // B fragments direct from global: lane (g,c) reads row (bn*256 + wc*64 + ni*16 + c),
  // cols k0 + ks*32 + g*8 -- 64B segments per 16-lane group, L2-served.
  const bfu* srcBd = W + (size_t)(bn * 256 + wc * 64 + c) * K + g * 8;
  short8 bD[4][2];
#define LOADB(k0) { _Pragma("unroll") for (int ni = 0; ni < 4; ++ni) \
    _Pragma("unroll") for (int ks = 0; ks < 2; ++ks) \
      bD[ni][ks] = *reinterpret_cast<const short8*>(srcBd + (size_t)(ni * 16) * K + (k0) + ks * 32); }

  short8 aF[5][2];
  const int swzR = ((c & 7) << 3);                 // read-side swizzle (elems)

#define LDA(cur, mh, CNT) { _Pragma("unroll") for (int mi2 = 0; mi2 < (CNT); ++mi2) \
    _Pragma("unroll") for (int ks = 0; ks < 2; ++ks) \
      aF[mi2][ks] = *reinterpret_cast<const short8*>( \
        AB(cur) + (((mh) ? rb1 : rb0) + mi2 * 16 + c) * 64 + ((ks * 32 + g * 8) ^ swzR)); }

  f32x4 acc[9][4];
  const f32x4 zero = {0.f, 0.f, 0.f, 0.f};
#pragma unroll
  for (int mi = 0; mi < 9; ++mi)
#pragma unroll
    for (int ni = 0; ni < 4; ++ni) acc[mi][ni] = zero;

#define PH_MFMA(mh, nh, CNT) { __builtin_amdgcn_s_setprio(1); \
    _Pragma("unroll") for (int mi2 = 0; mi2 < (CNT); ++mi2) \
    _Pragma("unroll") for (int ni2 = 0; ni2 < 2; ++ni2) \
    _Pragma("unroll") for (int ks = 0; ks < 2; ++ks) \
      acc[(mh) * 5 + mi2][(nh) * 2 + ni2] = \
        MFMA16(aF[mi2][ks], bD[(nh) * 2 + ni2][ks], acc[(mh) * 5 + mi2][(nh) * 2 + ni2]); \
    __builtin_amdgcn_s_setprio(0); }

  // ---- prologue: stage A(0) (5 loads) + load B(0) (8 reg loads); drain the A-stages only
  STAGE_A(0, 0, 0); STAGE_A(0, 1, 0); STAGE_A(0, 2, 0); STAGE_A(0, 3, 0); STAGE_A(0, 4, 0);
  LOADB(0);
  asm volatile("s_waitcnt vmcnt(8)" ::: "memory");
  __builtin_amdgcn_s_barrier();

  int cur = 0;
  for (int t = 0; t < nt - 1; ++t) {
    const int k1 = (t + 1) * 64;
    // p0: quadrant (0,0); ds-read 5 mh0 A-frags; stage all 5 A chunks of tile t+1
    LDA(cur, 0, 5);
    STAGE_A(cur ^ 1, 0, k1); STAGE_A(cur ^ 1, 1, k1);
    STAGE_A(cur ^ 1, 2, k1); STAGE_A(cur ^ 1, 3, k1); STAGE_A(cur ^ 1, 4, k1);
    __builtin_amdgcn_s_barrier();
    PH_MFMA(0, 0, 5);
    __builtin_amdgcn_s_barrier();
    // p1: quadrant (0,1) -- pure MFMA phase (aF reused, bD nh=1 already in registers)
    PH_MFMA(0, 1, 5);
    __builtin_amdgcn_s_barrier();
    // p2: quadrant (1,0); ds-read 4 mh1 A-frags
    LDA(cur, 1, 4);
    __builtin_amdgcn_s_barrier();
    PH_MFMA(1, 0, 4);
    __builtin_amdgcn_s_barrier();
    // p3: quadrant (1,1); then load B(t+1) and drain the A(t+1) stages (3-phase lead)
    PH_MFMA(1, 1, 4);
    LOADB(k1);
    asm volatile("s_waitcnt vmcnt(8)" ::: "memory");
    __builtin_amdgcn_s_barrier();
    cur ^= 1;
  }
  // ---- last tile: everything already staged/loaded and drained
  LDA(cur, 0, 5);
  __builtin_amdgcn_s_barrier();
  PH_MFMA(0, 0, 5);
  __builtin_amdgcn_s_barrier();
  PH_MFMA(0, 1, 5);
  __builtin_amdgcn_s_barrier();
  LDA(cur, 1, 4);
  PH_MFMA(1, 0, 4);
  PH_MFMA(1, 1, 4);

  // ---- epilogue (nt even => last tile used buf1; buf0 [0,40960) is dead -> bounce)
  const bool isCt = (RT > 0) && (bn * 256 >= colsplit);

  if (isCt) {
    const int RTl = (RT > 0 ? RT : 1);
    short* bw = (short*)lds + w * 2432;   // 16 x 152 per-wave tile
#pragma unroll
    for (int ni = 0; ni < 4; ++ni) {
      const float bs = bias[bn * 256 + wc * 64 + ni * 16 + c];
#pragma unroll
      for (int mh = 0; mh < 2; ++mh)
#pragma unroll
        for (int mi2 = 0; mi2 < 5; ++mi2) {
          if (mh == 1 && mi2 == 4) continue;
          const int qlb = wr ? (mh ? 0 : 64) : (mh ? 80 : 0);
          u16x4 pk;
#pragma unroll
          for (int r = 0; r < 4; ++r) pk[r] = f2bf(acc[mh * 5 + mi2][ni][r] + bs);
          *reinterpret_cast<u16x4*>(&bw[c * 152 + qlb + mi2 * 16 + g * 4]) = pk;
        }
#pragma unroll
      for (int it = 0; it < 5; ++it) {
        const int idx = it * 64 + lane;          // 0..287 (16 dd x 18 q8)
        if (idx < 288) {
          const int dd = idx / 18, q8 = idx - dd * 18;
          short8 vx = *reinterpret_cast<const short8*>(&bw[dd * 152 + q8 * 8]);
          const int colp = bn * 256 + wc * 64 + ni * 16 + dd - colsplit;
          const int hh = colp >> 6, dl = colp & 63;
          const int qg = bm * 288 + wr * 144 + q8 * 8;
          const int bb = qg / RTl, q0 = qg - bb * RTl;
          *reinterpret_cast<short8*>(Ct + ((size_t)(bb * 16 + hh) * 64 + dl) * RTl + q0) = vx;
        }
      }
    }
  } else if (Cf) {
    float* bwf = (float*)lds + w * 1088;
    float bs4[4];
#pragma unroll
    for (int ni = 0; ni < 4; ++ni) bs4[ni] = bias[bn * 256 + wc * 64 + ni * 16 + c];
#pragma unroll
    for (int mh = 0; mh < 2; ++mh)
#pragma unroll
      for (int mi2 = 0; mi2 < 5; ++mi2) {
        if (mh == 1 && mi2 == 4) continue;
#pragma unroll
        for (int ni = 0; ni < 4; ++ni)
#pragma unroll
          for (int r = 0; r < 4; ++r)
            bwf[(g * 4 + r) * 68 + ni * 16 + c] = acc[mh * 5 + mi2][ni][r] + bs4[ni];
#pragma unroll
        for (int p = 0; p < 4; ++p) {
          const int rr = lane >> 2;
          const int ch = p * 4 + (lane & 3);
          f32x4 vx = *reinterpret_cast<const f32x4*>(&bwf[rr * 68 + ch * 4]);
          const int row = bm * 288 + (mh ? rb1 : rb0) + mi2 * 16 + rr;
          *reinterpret_cast<f32x4*>(Cf + (size_t)row * ldc + bn * 256 + wc * 64 + ch * 4) = vx;
        }
      }
  } else {
    short* bw = (short*)lds + w * 1216;
    float bs4[4];
#pragma unroll
    for (int ni = 0; ni < 4; ++ni) bs4[ni] = bias[bn * 256 + wc * 64 + ni * 16 + c];
#pragma unroll
    for (int mh = 0; mh < 2; ++mh)
#pragma unroll
      for (int mi2 = 0; mi2 < 5; ++mi2) {
        if (mh == 1 && mi2 == 4) continue;
#pragma unroll
        for (int ni = 0; ni < 4; ++ni)
#pragma unroll
          for (int r = 0; r < 4; ++r)
            bw[(g * 4 + r) * 72 + ni * 16 + c] = (short)f2bf(acc[mh * 5 + mi2][ni][r] + bs4[ni]);
#pragma unroll
        for (int half = 0; half < 2; ++half) {
          const int rr = (lane >> 3) + half * 8;
          const int cc2 = (lane & 7) * 8;
          short8 vx = *reinterpret_cast<const short8*>(&bw[rr * 72 + cc2]);
          const int grow = bm * 288 + (mh ? rb1 : rb0) + mi2 * 16 + rr;
          *reinterpret_cast<short8*>(Cb + (size_t)grow * ldc + bn * 256 + wc * 64 + cc2) = vx;
        }
      }
  }
#undef AB
#undef STAGE_A
#undef LOADB
#undef LDA
#undef PH_MFMA
}

// ---------------------------------------------------------------- swizzled per-wave P-tile offsets
__device__ __forceinline__ int pvt_off(int q, int kbyte) { return q * 256 + (kbyte ^ ((q & 7) << 4)); }

// ---------------------------------------------------------------- fused bidirectional attention, one block per (b,h)
__global__ __launch_bounds__(256) void attn_bi(
    const bfu* __restrict__ Q, const bfu* __restrict__ Kl,
    const bfu* __restrict__ LVt, const bfu* __restrict__ VVt,
    const float* __restrict__ mask,
    bfu* __restrict__ xv, bfu* __restrict__ xl)
{
  __shared__ short Ks[128 * 64];      // 16 KB, swizzled
  __shared__ short LVs[64 * 128];     // 16 KB, swizzled within 128B half-rows
  __shared__ short PvT[4][2048];      // per-wave 16q x 128k tile ([q][k] swizzled); also bounce buf
  __shared__ short PkT[4][128 * 24];  // per-wave 128k x 16q tile ([k][q], 48B rows) for xl A-frags
  __shared__ float cpart[4][128];

  const int bh = blockIdx.x;
  const int b = bh >> 4, h = bh & 15;
  const int t = threadIdx.x, l = t & 63, w = t >> 6;
  const int g = l >> 4, c = l & 15;

  const bfu* Qp  = Q   + ((size_t)b * 576 * 1024 + h * 64);
  const bfu* Kp  = Kl  + ((size_t)b * 128 * 1024 + h * 64);
  const bfu* LVp = LVt + (size_t)bh * 64 * 128;
  const bfu* VVp = VVt + (size_t)bh * 64 * 576;
  const f32x4 zero = {0.f, 0.f, 0.f, 0.f};

  {
    const int kr = l >> 3;
    const bfu* sK = Kp + (size_t)(w * 8 + kr) * 1024 + (((l & 7) ^ kr) * 8);
#pragma unroll
    for (int i = 0; i < 4; ++i)
      gload_lds16(sK + (size_t)(i * 32) * 1024, (void*)&Ks[(i * 32 + w * 8) * 64]);
    const int lr = l >> 4;
    const int key = (w * 4 + lr) & 7;
    const bfu* sLV = LVp + (size_t)(w * 4 + lr) * 128 + ((l >> 3) & 1) * 64 + (((l & 7) ^ key) * 8);
#pragma unroll
    for (int i = 0; i < 4; ++i)
      gload_lds16(sLV + (size_t)(i * 16) * 128, (void*)&LVs[(i * 16 + w * 4) * 128]);
  }
  float mk[8];
#pragma unroll
  for (int kt = 0; kt < 8; ++kt) mk[kt] = mask[kt * 16 + c];
  __syncthreads();

  char* myPv = (char*)&PvT[w][0];
  short* myPk = &PkT[w][0];
  float colacc[8] = {0, 0, 0, 0, 0, 0, 0, 0};
  f32x4 xlacc[2][4];
#pragma unroll
  for (int kt2 = 0; kt2 < 2; ++kt2)
#pragma unroll
    for (int dt = 0; dt < 4; ++dt) xlacc[kt2][dt] = zero;

  for (int it = 0; it < 9; ++it) {
    const int qt = it * 4 + w;
    f32x4 sacc[8];
#pragma unroll
    for (int kt = 0; kt < 8; ++kt) sacc[kt] = zero;
    __builtin_amdgcn_s_setprio(1);
#pragma unroll
    for (int kk = 0; kk < 2; ++kk) {
      short8 aq = *reinterpret_cast<const short8*>(Qp + (size_t)(qt * 16 + c) * 1024 + kk * 32 + g * 8);
#pragma unroll
      for (int kt = 0; kt < 8; ++kt) {
        short8 bk = *reinterpret_cast<const short8*>(
            &Ks[(kt * 16 + c) * 64 + (((kk * 4 + g) ^ (c & 7)) * 8)]);
        sacc[kt] = MFMA16(aq, bk, sacc[kt]);
      }
    }
    __builtin_amdgcn_s_setprio(0);

    float rs[4] = {0, 0, 0, 0};
#pragma unroll
    for (int kt = 0; kt < 8; ++kt) {
      float ca = 0.f;
      u16x4 pk;
#pragma unroll
      for (int r = 0; r < 4; ++r) {
        float Ev = __expf(fmaf(sacc[kt][r], SCALE_QK, mk[kt]));
        rs[r] += Ev;
        ca += Ev;
        pk[r] = f2bf(Ev);
        *reinterpret_cast<unsigned short*>(myPv + pvt_off(g * 4 + r, 2 * (kt * 16 + c))) = pk[r];
      }
      colacc[kt] += ca;
      *reinterpret_cast<u16x4*>(&myPk[(kt * 16 + c) * 24 + g * 4]) = pk;
    }
#pragma unroll
    for (int r = 0; r < 4; ++r) {
      rs[r] += __shfl_xor(rs[r], 1);
      rs[r] += __shfl_xor(rs[r], 2);
      rs[r] += __shfl_xor(rs[r], 4);
      rs[r] += __shfl_xor(rs[r], 8);
    }

    short8 av[4];
#pragma unroll
    for (int kc = 0; kc < 4; ++kc)
      av[kc] = *reinterpret_cast<const short8*>(myPv + pvt_off(c, kc * 64 + g * 16));
    f32x4 oxv[4];
#pragma unroll
    for (int dt = 0; dt < 4; ++dt) oxv[dt] = zero;
    __builtin_amdgcn_s_setprio(1);
#pragma unroll
    for (int dt = 0; dt < 4; ++dt)
#pragma unroll
      for (int kc = 0; kc < 4; ++kc) {
        short8 bv = *reinterpret_cast<const short8*>(
            &LVs[(dt * 16 + c) * 128 + (kc >> 1) * 64 + ((((kc & 1) * 4 + g) ^ (c & 7)) * 8)]);
        oxv[dt] = MFMA16(av[kc], bv, oxv[dt]);
      }
    __builtin_amdgcn_s_setprio(0);
#pragma unroll
    for (int r = 0; r < 4; ++r) rs[r] = 1.0f / rs[r];

    {
      short* bw = (short*)&PvT[w][0];
#pragma unroll
      for (int dt = 0; dt < 4; ++dt)
#pragma unroll
        for (int r = 0; r < 4; ++r)
          bw[(g * 4 + r) * 72 + dt * 16 + c] = (short)f2bf(oxv[dt][r] * rs[r]);
#pragma unroll
      for (int half = 0; half < 2; ++half) {
        const int rr = (l >> 3) + half * 8;
        const int cc = (l & 7) * 8;
        short8 vx = *reinterpret_cast<const short8*>(&bw[rr * 72 + cc]);
        *reinterpret_cast<short8*>(xv + (size_t)(b * 576 + qt * 16 + rr) * 1024 + h * 64 + cc) = vx;
      }
    }

    __syncthreads();   // all 4 PkT tiles of this iter ready

#pragma unroll
    for (int kt2 = 0; kt2 < 2; ++kt2) {
      const int krow = w * 32 + kt2 * 16 + c;
      short8 ap[2];
#pragma unroll
      for (int ks = 0; ks < 2; ++ks) {
        const int wq = ks * 2 + (g >> 1);
        ap[ks] = *reinterpret_cast<const short8*>(&PkT[wq][krow * 24 + (g & 1) * 8]);
      }
      __builtin_amdgcn_s_setprio(1);
#pragma unroll
      for (int dt = 0; dt < 4; ++dt) {
#pragma unroll
        for (int ks = 0; ks < 2; ++ks) {
          short8 bv = *reinterpret_cast<const short8*>(
              VVp + (size_t)(dt * 16 + c) * 576 + it * 64 + ks * 32 + g * 8);
          xlacc[kt2][dt] = MFMA16(ap[ks], bv, xlacc[kt2][dt]);
        }
      }
      __builtin_amdgcn_s_setprio(0);
    }
    __syncthreads();   // everyone done reading PkT before next iter overwrites
  }

#pragma unroll
  for (int kt = 0; kt < 8; ++kt) {
    colacc[kt] += __shfl_xor(colacc[kt], 16);
    colacc[kt] += __shfl_xor(colacc[kt], 32);
  }
  if (g == 0) {
#pragma unroll
    for (int kt = 0; kt < 8; ++kt) cpart[w][kt * 16 + c] = colacc[kt];
  }
  __syncthreads();

  short* bw = (short*)&PvT[w][0];
#pragma unroll
  for (int kt2 = 0; kt2 < 2; ++kt2) {
    float ci[4];
#pragma unroll
    for (int r = 0; r < 4; ++r) {
      const int k = w * 32 + kt2 * 16 + g * 4 + r;
      ci[r] = 1.0f / (cpart[0][k] + cpart[1][k] + cpart[2][k] + cpart[3][k]);
    }
#pragma unroll
    for (int dt = 0; dt < 4; ++dt)
#pragma unroll
      for (int r = 0; r < 4; ++r)
        bw[(g * 4 + r) * 72 + dt * 16 + c] = (short)f2bf(xlacc[kt2][dt][r] * ci[r]);
#pragma unroll
    for (int half = 0; half < 2; ++half) {
      const int rr = (l >> 3) + half * 8;
      const int cc = (l & 7) * 8;
      short8 vx = *reinterpret_cast<const short8*>(&bw[rr * 72 + cc]);
      *reinterpret_cast<short8*>(xl + (size_t)(b * 128 + w * 32 + kt2 * 16 + rr) * 1024 + h * 64 + cc) = vx;
    }
  }
}

// ---------------------------------------------------------------- host
static inline int cvt_grid(int n4) {
  int g = (n4 + 255) / 256;
  return g > 4096 ? 4096 : g;
}

extern "C" void kernel_launch(void* const* d_in, const int* in_sizes, int n_in,
                              void* d_out, int out_size, void* d_ws, size_t ws_size,
                              hipStream_t stream)
{
  const float* v    = (const float*)d_in[0];
  const float* lx   = (const float*)d_in[1];
  const float* mask = (const float*)d_in[2];
  const float* Wvq  = (const float*)d_in[3];
  const float* bvq  = (const float*)d_in[4];
  const float* Wlk  = (const float*)d_in[5];
  const float* blk  = (const float*)d_in[6];
  const float* Wvv  = (const float*)d_in[7];
  const float* bvv  = (const float*)d_in[8];
  const float* Wlv  = (const float*)d_in[9];
  const float* blv  = (const float*)d_in[10];
  const float* Wvo  = (const float*)d_in[11];
  const float* bvo  = (const float*)d_in[12];
  const float* Wlo  = (const float*)d_in[13];
  const float* blo  = (const float*)d_in[14];

  float* out_xv = (float*)d_out;                       // 18432 x 1024
  float* out_xl = out_xv + (size_t)18432 * 1024;       // 4096 x 768

  bfu* ws   = (bfu*)d_ws;
  bfu* vb   = ws;                      // 18874368 (later aliased as xv bf16)
  bfu* lb   = vb   + 18874368;         // 3145728
  bfu* wqv  = lb   + 3145728;          // 2097152  [Wvq ; Wvv] (2048x1024)
  bfu* wklv = wqv  + 2097152;          // 1572864  [Wlk ; Wlv] (2048x768)
  bfu* wvo  = wklv + 1572864;          // 1048576
  bfu* wlo  = wvo  + 1048576;          // 786432
  bfu* Qb   = wlo  + 786432;           // 18874368  [18432][1024] bf16
  bfu* VVt  = Qb   + 18874368;         // 18874368  [bh][64][576]
  bfu* Kb   = VVt  + 18874368;         // 4194304   [4096][1024] (later aliased as xl bf16)
  bfu* LVt  = Kb   + 4194304;          // 4194304   [bh][64][128]
  float* biasqv = (float*)(LVt + 4194304);   // 2048 f32  [bvq ; bvv]
  float* biaskl = biasqv + 2048;             // 2048 f32  [blk ; blv]

  // 1) converts + bias concat
  cvt_f32_bf16<<<cvt_grid(18874368 / 4), 256, 0, stream>>>(v, vb, 18874368 / 4);
  CvtArgs ca;
  ca.src[0] = lx;  ca.dst[0] = lb;             ca.n4[0] = 3145728 / 4;
  ca.src[1] = Wvq; ca.dst[1] = wqv;            ca.n4[1] = 1048576 / 4;
  ca.src[2] = Wvv; ca.dst[2] = wqv + 1048576;  ca.n4[2] = 1048576 / 4;
  ca.src[3] = Wlk; ca.dst[3] = wklv;           ca.n4[3] = 786432 / 4;
  ca.src[4] = Wlv; ca.dst[4] = wklv + 786432;  ca.n4[4] = 786432 / 4;
  ca.src[5] = Wvo; ca.dst[5] = wvo;            ca.n4[5] = 1048576 / 4;
  ca.src[6] = Wlo; ca.dst[6] = wlo;            ca.n4[6] = 786432 / 4;
  cvt_multi<<<dim3(1024, 7), 256, 0, stream>>>(ca);
  bias_concat<<<4, 256, 0, stream>>>(bvq, bvv, blk, blv, biasqv, biaskl);

  // 2) projections: QV on 288x256 B-direct kernel (512 blocks, 2 blocks/CU); KL on 128-tile
  gemm288<576><<<64 * 8, 512, 0, stream>>>(vb, wqv, biasqv, Qb, nullptr, VVt, 1024, 1024,
                                           18432, 2048, 1024, 8);
  gemm_bt<<<32 * 16, 256, 0, stream>>>(lb, wklv, biaskl, Kb, nullptr, LVt, 128, 1024, 1024,
                                       4096, 2048, 768, 16);

  // 3) fused attention (xv -> vb alias, xl -> Kb alias)
  attn_bi<<<512, 256, 0, stream>>>(Qb, Kb, LVt, VVt, mask, vb, Kb);

  // 4) output GEMMs: out_xv on 288x256 kernel (256 blocks), out_xl on 128-tile
  gemm288<0><<<64 * 4, 512, 0, stream>>>(vb, wvo, bvo, nullptr, out_xv, nullptr, 1 << 30, 1024,
                                         18432, 1024, 1024, 4);
  gemm_bt<<<32 * 6, 256, 0, stream>>>(Kb, wlo, blo, nullptr, out_xl, nullptr, 0, 768, 768,
                                      4096, 768, 1024, 6);
}

// Round 16
// 255.148 us; speedup vs baseline: 1.2528x; 1.2528x over previous
//
#include <hip/hip_runtime.h>
#include <stdint.h>

// BiMultiHeadAttention (GLIP bi-attention), MI355X bf16 MFMA pipeline.
// B=32 VN=576 LN=128 E=1024 H=16 D=64, V_DIM=1024 L_DIM=768, SCALE=0.25.
// R16 = revert to R14 best-known (256.4 us): gemm288 with B in LDS, fused attn_bi.

typedef unsigned short bfu;   // bf16 storage
typedef __attribute__((ext_vector_type(4))) float f32x4;
typedef __attribute__((ext_vector_type(8))) short short8;
typedef __attribute__((ext_vector_type(4))) unsigned short u16x4;

#define MFMA16(a,b,c) __builtin_amdgcn_mfma_f32_16x16x32_bf16((a),(b),(c),0,0,0)
#define SCALE_QK 0.25f

__device__ __forceinline__ unsigned short f2bf(float x) {
  unsigned int u = __float_as_uint(x);
  u += 0x7fffu + ((u >> 16) & 1u);   // round-to-nearest-even
  return (unsigned short)(u >> 16);
}

__device__ __forceinline__ void gload_lds16(const void* g, void* l) {
  __builtin_amdgcn_global_load_lds(
      reinterpret_cast<__attribute__((address_space(1))) void*>(
          reinterpret_cast<uintptr_t>(g)),
      reinterpret_cast<__attribute__((address_space(3))) void*>(
          (uint32_t)reinterpret_cast<uintptr_t>(l)),
      16, 0, 0);
}

// ---------------------------------------------------------------- converts
__global__ void cvt_f32_bf16(const float* __restrict__ x, bfu* __restrict__ y, int n4) {
  for (int i = blockIdx.x * blockDim.x + threadIdx.x; i < n4; i += gridDim.x * blockDim.x) {
    const float4 f = *reinterpret_cast<const float4*>(x + (size_t)i * 4);
    u16x4 o;
    o[0] = f2bf(f.x); o[1] = f2bf(f.y); o[2] = f2bf(f.z); o[3] = f2bf(f.w);
    *reinterpret_cast<u16x4*>(y + (size_t)i * 4) = o;
  }
}

struct CvtArgs {
  const float* src[7];
  bfu* dst[7];
  int n4[7];
};

__global__ void cvt_multi(CvtArgs a) {
  const int s = blockIdx.y;
  const float* __restrict__ x = a.src[s];
  bfu* __restrict__ y = a.dst[s];
  const int n4 = a.n4[s];
  for (int i = blockIdx.x * blockDim.x + threadIdx.x; i < n4; i += gridDim.x * blockDim.x) {
    const float4 f = *reinterpret_cast<const float4*>(x + (size_t)i * 4);
    u16x4 o;
    o[0] = f2bf(f.x); o[1] = f2bf(f.y); o[2] = f2bf(f.z); o[3] = f2bf(f.w);
    *reinterpret_cast<u16x4*>(y + (size_t)i * 4) = o;
  }
}

// bias concat: one dispatch replaces 4 d2d memcpies
__global__ void bias_concat(const float* __restrict__ a, const float* __restrict__ b,
                            const float* __restrict__ c2, const float* __restrict__ d,
                            float* __restrict__ qv, float* __restrict__ kl) {
  const int i = threadIdx.x * 4;
  const float4* s;
  float* o;
  switch (blockIdx.x) {
    case 0: s = (const float4*)a;  o = qv;        break;
    case 1: s = (const float4*)b;  o = qv + 1024; break;
    case 2: s = (const float4*)c2; o = kl;        break;
    default: s = (const float4*)d; o = kl + 1024; break;
  }
  *reinterpret_cast<float4*>(o + i) = s[threadIdx.x];
}

// ---------------------------------------------------------------- GEMM 128-tile (m97 structure) — R5 version
__global__ __launch_bounds__(256) void gemm_bt(
    const bfu* __restrict__ A, const bfu* __restrict__ W, const float* __restrict__ bias,
    bfu* __restrict__ Cb, float* __restrict__ Cf, bfu* __restrict__ Ct, int R, int colsplit,
    int ldc, int M, int N, int K, int nbn)
{
  __shared__ bfu As[128 * 32];
  __shared__ bfu Bs[128 * 32];
  const int nbm = M >> 7;
  const int bid = blockIdx.x;
  int bm, bn;
  if ((nbm & 7) == 0) {             // bijective XCD-aware swizzle
    const int xcd = bid & 7, j = bid >> 3;
    const int jm = j / nbn;
    bm = xcd * (nbm >> 3) + jm;
    bn = j - jm * nbn;
  } else { bm = bid / nbn; bn = bid - (bid / nbn) * nbn; }

  const int t = threadIdx.x, l = t & 63, w = t >> 6;
  const int g = l >> 4, c = l & 15;
  const int wr = (w >> 1) * 64, wc = (w & 1) * 64;

  f32x4 zero = {0.f, 0.f, 0.f, 0.f};
  f32x4 acc[4][4];
  for (int m = 0; m < 4; ++m)
    for (int n = 0; n < 4; ++n) acc[m][n] = zero;

  const int rowA = l >> 2;
  const int kb   = (l & 3) * 16;

  for (int k0 = 0; k0 < K; k0 += 32) {
#pragma unroll
    for (int i = 0; i < 2; ++i) {
      int chunk = w * 2 + i;
      int r = chunk * 16 + rowA;
      const char* ga = (const char*)(A + (size_t)(bm * 128 + r) * K + k0) + kb;
      const char* gb = (const char*)(W + (size_t)(bn * 128 + r) * K + k0) + kb;
      gload_lds16(ga, (char*)As + chunk * 1024);
      gload_lds16(gb, (char*)Bs + chunk * 1024);
    }
    __syncthreads();
    short8 a[4], bf[4];
#pragma unroll
    for (int m = 0; m < 4; ++m)
      a[m] = *reinterpret_cast<const short8*>(&As[(wr + m * 16 + c) * 32 + g * 8]);
#pragma unroll
    for (int n = 0; n < 4; ++n)
      bf[n] = *reinterpret_cast<const short8*>(&Bs[(wc + n * 16 + c) * 32 + g * 8]);
#pragma unroll
    for (int m = 0; m < 4; ++m)
#pragma unroll
      for (int n = 0; n < 4; ++n)
        acc[m][n] = MFMA16(a[m], bf[n], acc[m][n]);
    __syncthreads();
  }

#pragma unroll
  for (int n = 0; n < 4; ++n) {
    const int col = bn * 128 + wc + n * 16 + c;
    const float bs = bias[col];
    if (col >= colsplit) {
      const int colp = col - colsplit;
      const int hh = colp >> 6, dd = colp & 63;
#pragma unroll
      for (int m = 0; m < 4; ++m) {
        const int row0 = bm * 128 + wr + m * 16 + g * 4;
        const int bb = row0 / R, q0 = row0 - bb * R;
        u16x4 pk;
#pragma unroll
        for (int r = 0; r < 4; ++r) pk[r] = f2bf(acc[m][n][r] + bs);
        *reinterpret_cast<u16x4*>(Ct + ((size_t)(bb * 16 + hh) * 64 + dd) * R + q0) = pk;
      }
    } else {
#pragma unroll
      for (int m = 0; m < 4; ++m) {
        const int row0 = bm * 128 + wr + m * 16 + g * 4;
#pragma unroll
        for (int r = 0; r < 4; ++r) {
          float val = acc[m][n][r] + bs;
          size_t idx = (size_t)(row0 + r) * ldc + col;
          if (Cf) Cf[idx] = val;
          else    Cb[idx] = f2bf(val);
        }
      }
    }
  }
}

// ---------------------------------------------------------------- GEMM 288x256-tile, 8-phase schedule (R12/R14 best)
template<int RT>
__global__ __launch_bounds__(512, 2) void gemm288(
    const bfu* __restrict__ A, const bfu* __restrict__ W, const float* __restrict__ bias,
    bfu* __restrict__ Cb, float* __restrict__ Cf, bfu* __restrict__ Ct, int colsplit,
    int ldc, int M, int N, int K, int nbn)
{
  __shared__ bfu lds[2 * 36864];      // 147456 B

  const int tid = threadIdx.x;
  const int w = tid >> 6, lane = tid & 63;
  const int g = lane >> 4, c = lane & 15;
  const int wr = w >> 2, wc = w & 3;
  const int rb0 = wr ? 208 : 0;
  const int rb1 = wr ? 144 : 80;

  const int nbm = M / 288;
  int bm, bn;
  { const int xcd = blockIdx.x & 7, j = blockIdx.x >> 3;
    const int jm = j / nbn; bm = xcd * (nbm >> 3) + jm; bn = j - jm * nbn; }

  const int nt = K >> 6;

  const int srow8 = lane >> 3;
  const int sslot = lane & 7;
  const int swzE  = ((sslot * 16) ^ (srow8 << 4)) >> 1;
  const bfu* srcA = A + (size_t)(bm * 288 + 8 * w + srow8) * K + swzE;
  const bfu* srcB = W + (size_t)(bn * 256 + 8 * w + srow8) * K + swzE;

#define AB(cur) (lds + (cur) * 36864)
#define BB(cur) (lds + (cur) * 36864 + 20480)
#define STAGE_A(cur, j, k0) gload_lds16(srcA + (size_t)(64 * (j)) * K + (k0), \
    (void*)(AB(cur) + (64 * (j) + 8 * w) * 64))
#define STAGE_B(cur, j, k0) gload_lds16(srcB + (size_t)(64 * (j)) * K + (k0), \
    (void*)(BB(cur) + (64 * (j) + 8 * w) * 64))

  short8 aF[5][2], bF[4][2];
  const int swzR = ((c & 7) << 3);

#define LDA(cur, mh, CNT) { _Pragma("unroll") for (int mi2 = 0; mi2 < (CNT); ++mi2) \
    _Pragma("unroll") for (int ks = 0; ks < 2; ++ks) \
      aF[mi2][ks] = *reinterpret_cast<const short8*>( \
        AB(cur) + (((mh) ? rb1 : rb0) + mi2 * 16 + c) * 64 + ((ks * 32 + g * 8) ^ swzR)); }
#define LDB(cur, nh) { _Pragma("unroll") for (int ni2 = 0; ni2 < 2; ++ni2) \
    _Pragma("unroll") for (int ks = 0; ks < 2; ++ks) \
      bF[(nh) * 2 + ni2][ks] = *reinterpret_cast<const short8*>( \
        BB(cur) + (wc * 64 + (nh) * 32 + ni2 * 16 + c) * 64 + ((ks * 32 + g * 8) ^ swzR)); }

  f32x4 acc[9][4];
  const f32x4 zero = {0.f, 0.f, 0.f, 0.f};
#pragma unroll
  for (int mi = 0; mi < 9; ++mi)
#pragma unroll
    for (int ni = 0; ni < 4; ++ni) acc[mi][ni] = zero;

#define PH_MFMA(mh, nh, CNT) { __builtin_amdgcn_s_setprio(1); \
    _Pragma("unroll") for (int mi2 = 0; mi2 < (CNT); ++mi2) \
    _Pragma("unroll") for (int ni2 = 0; ni2 < 2; ++ni2) \
    _Pragma("unroll") for (int ks = 0; ks < 2; ++ks) \
      acc[(mh) * 5 + mi2][(nh) * 2 + ni2] = \
        MFMA16(aF[mi2][ks], bF[(nh) * 2 + ni2][ks], acc[(mh) * 5 + mi2][(nh) * 2 + ni2]); \
    __builtin_amdgcn_s_setprio(0); }

  // ---- prologue
  STAGE_B(0, 0, 0); STAGE_B(0, 1, 0); STAGE_B(0, 2, 0); STAGE_B(0, 3, 0);
  STAGE_A(0, 0, 0); STAGE_A(0, 1, 0); STAGE_A(0, 3, 0); STAGE_A(0, 4, 0); STAGE_A(0, 2, 0);
  asm volatile("s_waitcnt vmcnt(0)" ::: "memory");
  __builtin_amdgcn_s_barrier();

  int cur = 0;
  for (int t = 0; t < nt - 1; ++t) {
    const int k1 = (t + 1) * 64;
    LDB(cur, 0); LDA(cur, 0, 5);
    STAGE_B(cur ^ 1, 0, k1); STAGE_B(cur ^ 1, 1, k1);
    STAGE_B(cur ^ 1, 2, k1); STAGE_B(cur ^ 1, 3, k1);
    __builtin_amdgcn_s_barrier();
    PH_MFMA(0, 0, 5);
    __builtin_amdgcn_s_barrier();
    LDB(cur, 1);
    STAGE_A(cur ^ 1, 0, k1); STAGE_A(cur ^ 1, 1, k1);
    STAGE_A(cur ^ 1, 3, k1); STAGE_A(cur ^ 1, 4, k1);
    asm volatile("s_waitcnt vmcnt(8)" ::: "memory");
    __builtin_amdgcn_s_barrier();
    PH_MFMA(0, 1, 5);
    __builtin_amdgcn_s_barrier();
    LDA(cur, 1, 4);
    STAGE_A(cur ^ 1, 2, k1);
    __builtin_amdgcn_s_barrier();
    PH_MFMA(1, 0, 4);
    __builtin_amdgcn_s_barrier();
    asm volatile("s_waitcnt vmcnt(1)" ::: "memory");
    __builtin_amdgcn_s_barrier();
    PH_MFMA(1, 1, 4);
    __builtin_amdgcn_s_barrier();
    cur ^= 1;
  }
  LDB(cur, 0); LDA(cur, 0, 5);
  __builtin_amdgcn_s_barrier();
  PH_MFMA(0, 0, 5);
  __builtin_amdgcn_s_barrier();
  LDB(cur, 1);
  asm volatile("s_waitcnt vmcnt(0)" ::: "memory");
  __builtin_amdgcn_s_barrier();
  PH_MFMA(0, 1, 5);
  __builtin_amdgcn_s_barrier();
  LDA(cur, 1, 4);
  PH_MFMA(1, 0, 4);
  PH_MFMA(1, 1, 4);

  // ---- epilogue (buf0 dead -> bounce)
  const bool isCt = (RT > 0) && (bn * 256 >= colsplit);

  if (isCt) {
    const int RTl = (RT > 0 ? RT : 1);
    short* bw = (short*)lds + w * 2432;   // 16 x 152
#pragma unroll
    for (int ni = 0; ni < 4; ++ni) {
      const float bs = bias[bn * 256 + wc * 64 + ni * 16 + c];
#pragma unroll
      for (int mh = 0; mh < 2; ++mh)
#pragma unroll
        for (int mi2 = 0; mi2 < 5; ++mi2) {
          if (mh == 1 && mi2 == 4) continue;
          const int qlb = wr ? (mh ? 0 : 64) : (mh ? 80 : 0);
          u16x4 pk;
#pragma unroll
          for (int r = 0; r < 4; ++r) pk[r] = f2bf(acc[mh * 5 + mi2][ni][r] + bs);
          *reinterpret_cast<u16x4*>(&bw[c * 152 + qlb + mi2 * 16 + g * 4]) = pk;
        }
#pragma unroll
      for (int it = 0; it < 5; ++it) {
        const int idx = it * 64 + lane;
        if (idx < 288) {
          const int dd = idx / 18, q8 = idx - dd * 18;
          short8 vx = *reinterpret_cast<const short8*>(&bw[dd * 152 + q8 * 8]);
          const int colp = bn * 256 + wc * 64 + ni * 16 + dd - colsplit;
          const int hh = colp >> 6, dl = colp & 63;
          const int qg = bm * 288 + wr * 144 + q8 * 8;
          const int bb = qg / RTl, q0 = qg - bb * RTl;
          *reinterpret_cast<short8*>(Ct + ((size_t)(bb * 16 + hh) * 64 + dl) * RTl + q0) = vx;
        }
      }
    }
  } else if (Cf) {
    float* bwf = (float*)lds + w * 1088;
    float bs4[4];
#pragma unroll
    for (int ni = 0; ni < 4; ++ni) bs4[ni] = bias[bn * 256 + wc * 64 + ni * 16 + c];
#pragma unroll
    for (int mh = 0; mh < 2; ++mh)
#pragma unroll
      for (int mi2 = 0; mi2 < 5; ++mi2) {
        if (mh == 1 && mi2 == 4) continue;
#pragma unroll
        for (int ni = 0; ni < 4; ++ni)
#pragma unroll
          for (int r = 0; r < 4; ++r)
            bwf[(g * 4 + r) * 68 + ni * 16 + c] = acc[mh * 5 + mi2][ni][r] + bs4[ni];
#pragma unroll
        for (int p = 0; p < 4; ++p) {
          const int rr = lane >> 2;
          const int ch = p * 4 + (lane & 3);
          f32x4 vx = *reinterpret_cast<const f32x4*>(&bwf[rr * 68 + ch * 4]);
          const int row = bm * 288 + (mh ? rb1 : rb0) + mi2 * 16 + rr;
          *reinterpret_cast<f32x4*>(Cf + (size_t)row * ldc + bn * 256 + wc * 64 + ch * 4) = vx;
        }
      }
  } else {
    short* bw = (short*)lds + w * 1216;
    float bs4[4];
#pragma unroll
    for (int ni = 0; ni < 4; ++ni) bs4[ni] = bias[bn * 256 + wc * 64 + ni * 16 + c];
#pragma unroll
    for (int mh = 0; mh < 2; ++mh)
#pragma unroll
      for (int mi2 = 0; mi2 < 5; ++mi2) {
        if (mh == 1 && mi2 == 4) continue;
#pragma unroll
        for (int ni = 0; ni < 4; ++ni)
#pragma unroll
          for (int r = 0; r < 4; ++r)
            bw[(g * 4 + r) * 72 + ni * 16 + c] = (short)f2bf(acc[mh * 5 + mi2][ni][r] + bs4[ni]);
#pragma unroll
        for (int half = 0; half < 2; ++half) {
          const int rr = (lane >> 3) + half * 8;
          const int cc2 = (lane & 7) * 8;
          short8 vx = *reinterpret_cast<const short8*>(&bw[rr * 72 + cc2]);
          const int grow = bm * 288 + (mh ? rb1 : rb0) + mi2 * 16 + rr;
          *reinterpret_cast<short8*>(Cb + (size_t)grow * ldc + bn * 256 + wc * 64 + cc2) = vx;
        }
      }
  }
#undef AB
#undef BB
#undef STAGE_A
#undef STAGE_B
#undef LDA
#undef LDB
#undef PH_MFMA
}

// ---------------------------------------------------------------- swizzled per-wave P-tile offsets
__device__ __forceinline__ int pvt_off(int q, int kbyte) { return q * 256 + (kbyte ^ ((q & 7) << 4)); }

// ---------------------------------------------------------------- fused bidirectional attention, one block per (b,h)
__global__ __launch_bounds__(256) void attn_bi(
    const bfu* __restrict__ Q, const bfu* __restrict__ Kl,
    const bfu* __restrict__ LVt, const bfu* __restrict__ VVt,
    const float* __restrict__ mask,
    bfu* __restrict__ xv, bfu* __restrict__ xl)
{
  __shared__ short Ks[128 * 64];      // 16 KB, swizzled
  __shared__ short LVs[64 * 128];     // 16 KB, swizzled within 128B half-rows
  __shared__ short PvT[4][2048];      // per-wave 16q x 128k tile ([q][k] swizzled); also bounce buf
  __shared__ short PkT[4][128 * 24];  // per-wave 128k x 16q tile ([k][q], 48B rows) for xl A-frags
  __shared__ float cpart[4][128];

  const int bh = blockIdx.x;
  const int b = bh >> 4, h = bh & 15;
  const int t = threadIdx.x, l = t & 63, w = t >> 6;
  const int g = l >> 4, c = l & 15;

  const bfu* Qp  = Q   + ((size_t)b * 576 * 1024 + h * 64);
  const bfu* Kp  = Kl  + ((size_t)b * 128 * 1024 + h * 64);
  const bfu* LVp = LVt + (size_t)bh * 64 * 128;
  const bfu* VVp = VVt + (size_t)bh * 64 * 576;
  const f32x4 zero = {0.f, 0.f, 0.f, 0.f};

  {
    const int kr = l >> 3;
    const bfu* sK = Kp + (size_t)(w * 8 + kr) * 1024 + (((l & 7) ^ kr) * 8);
#pragma unroll
    for (int i = 0; i < 4; ++i)
      gload_lds16(sK + (size_t)(i * 32) * 1024, (void*)&Ks[(i * 32 + w * 8) * 64]);
    const int lr = l >> 4;
    const int key = (w * 4 + lr) & 7;
    const bfu* sLV = LVp + (size_t)(w * 4 + lr) * 128 + ((l >> 3) & 1) * 64 + (((l & 7) ^ key) * 8);
#pragma unroll
    for (int i = 0; i < 4; ++i)
      gload_lds16(sLV + (size_t)(i * 16) * 128, (void*)&LVs[(i * 16 + w * 4) * 128]);
  }
  float mk[8];
#pragma unroll
  for (int kt = 0; kt < 8; ++kt) mk[kt] = mask[kt * 16 + c];
  __syncthreads();

  char* myPv = (char*)&PvT[w][0];
  short* myPk = &PkT[w][0];
  float colacc[8] = {0, 0, 0, 0, 0, 0, 0, 0};
  f32x4 xlacc[2][4];
#pragma unroll
  for (int kt2 = 0; kt2 < 2; ++kt2)
#pragma unroll
    for (int dt = 0; dt < 4; ++dt) xlacc[kt2][dt] = zero;

  for (int it = 0; it < 9; ++it) {
    const int qt = it * 4 + w;
    f32x4 sacc[8];
#pragma unroll
    for (int kt = 0; kt < 8; ++kt) sacc[kt] = zero;
    __builtin_amdgcn_s_setprio(1);
#pragma unroll
    for (int kk = 0; kk < 2; ++kk) {
      short8 aq = *reinterpret_cast<const short8*>(Qp + (size_t)(qt * 16 + c) * 1024 + kk * 32 + g * 8);
#pragma unroll
      for (int kt = 0; kt < 8; ++kt) {
        short8 bk = *reinterpret_cast<const short8*>(
            &Ks[(kt * 16 + c) * 64 + (((kk * 4 + g) ^ (c & 7)) * 8)]);
        sacc[kt] = MFMA16(aq, bk, sacc[kt]);
      }
    }
    __builtin_amdgcn_s_setprio(0);

    float rs[4] = {0, 0, 0, 0};
#pragma unroll
    for (int kt = 0; kt < 8; ++kt) {
      float ca = 0.f;
      u16x4 pk;
#pragma unroll
      for (int r = 0; r < 4; ++r) {
        float Ev = __expf(fmaf(sacc[kt][r], SCALE_QK, mk[kt]));
        rs[r] += Ev;
        ca += Ev;
        pk[r] = f2bf(Ev);
        *reinterpret_cast<unsigned short*>(myPv + pvt_off(g * 4 + r, 2 * (kt * 16 + c))) = pk[r];
      }
      colacc[kt] += ca;
      *reinterpret_cast<u16x4*>(&myPk[(kt * 16 + c) * 24 + g * 4]) = pk;
    }
#pragma unroll
    for (int r = 0; r < 4; ++r) {
      rs[r] += __shfl_xor(rs[r], 1);
      rs[r] += __shfl_xor(rs[r], 2);
      rs[r] += __shfl_xor(rs[r], 4);
      rs[r] += __shfl_xor(rs[r], 8);
    }

    short8 av[4];
#pragma unroll
    for (int kc = 0; kc < 4; ++kc)
      av[kc] = *reinterpret_cast<const short8*>(myPv + pvt_off(c, kc * 64 + g * 16));
    f32x4 oxv[4];
#pragma unroll
    for (int dt = 0; dt < 4; ++dt) oxv[dt] = zero;
    __builtin_amdgcn_s_setprio(1);
#pragma unroll
    for (int dt = 0; dt < 4; ++dt)
#pragma unroll
      for (int kc = 0; kc < 4; ++kc) {
        short8 bv = *reinterpret_cast<const short8*>(
            &LVs[(dt * 16 + c) * 128 + (kc >> 1) * 64 + ((((kc & 1) * 4 + g) ^ (c & 7)) * 8)]);
        oxv[dt] = MFMA16(av[kc], bv, oxv[dt]);
      }
    __builtin_amdgcn_s_setprio(0);
#pragma unroll
    for (int r = 0; r < 4; ++r) rs[r] = 1.0f / rs[r];

    {
      short* bw = (short*)&PvT[w][0];
#pragma unroll
      for (int dt = 0; dt < 4; ++dt)
#pragma unroll
        for (int r = 0; r < 4; ++r)
          bw[(g * 4 + r) * 72 + dt * 16 + c] = (short)f2bf(oxv[dt][r] * rs[r]);
#pragma unroll
      for (int half = 0; half < 2; ++half) {
        const int rr = (l >> 3) + half * 8;
        const int cc = (l & 7) * 8;
        short8 vx = *reinterpret_cast<const short8*>(&bw[rr * 72 + cc]);
        *reinterpret_cast<short8*>(xv + (size_t)(b * 576 + qt * 16 + rr) * 1024 + h * 64 + cc) = vx;
      }
    }

    __syncthreads();   // all 4 PkT tiles of this iter ready

#pragma unroll
    for (int kt2 = 0; kt2 < 2; ++kt2) {
      const int krow = w * 32 + kt2 * 16 + c;
      short8 ap[2];
#pragma unroll
      for (int ks = 0; ks < 2; ++ks) {
        const int wq = ks * 2 + (g >> 1);
        ap[ks] = *reinterpret_cast<const short8*>(&PkT[wq][krow * 24 + (g & 1) * 8]);
      }
      __builtin_amdgcn_s_setprio(1);
#pragma unroll
      for (int dt = 0; dt < 4; ++dt) {
#pragma unroll
        for (int ks = 0; ks < 2; ++ks) {
          short8 bv = *reinterpret_cast<const short8*>(
              VVp + (size_t)(dt * 16 + c) * 576 + it * 64 + ks * 32 + g * 8);
          xlacc[kt2][dt] = MFMA16(ap[ks], bv, xlacc[kt2][dt]);
        }
      }
      __builtin_amdgcn_s_setprio(0);
    }
    __syncthreads();   // everyone done reading PkT before next iter overwrites
  }

#pragma unroll
  for (int kt = 0; kt < 8; ++kt) {
    colacc[kt] += __shfl_xor(colacc[kt], 16);
    colacc[kt] += __shfl_xor(colacc[kt], 32);
  }
  if (g == 0) {
#pragma unroll
    for (int kt = 0; kt < 8; ++kt) cpart[w][kt * 16 + c] = colacc[kt];
  }
  __syncthreads();

  short* bw = (short*)&PvT[w][0];
#pragma unroll
  for (int kt2 = 0; kt2 < 2; ++kt2) {
    float ci[4];
#pragma unroll
    for (int r = 0; r < 4; ++r) {
      const int k = w * 32 + kt2 * 16 + g * 4 + r;
      ci[r] = 1.0f / (cpart[0][k] + cpart[1][k] + cpart[2][k] + cpart[3][k]);
    }
#pragma unroll
    for (int dt = 0; dt < 4; ++dt)
#pragma unroll
      for (int r = 0; r < 4; ++r)
        bw[(g * 4 + r) * 72 + dt * 16 + c] = (short)f2bf(xlacc[kt2][dt][r] * ci[r]);
#pragma unroll
    for (int half = 0; half < 2; ++half) {
      const int rr = (l >> 3) + half * 8;
      const int cc = (l & 7) * 8;
      short8 vx = *reinterpret_cast<const short8*>(&bw[rr * 72 + cc]);
      *reinterpret_cast<short8*>(xl + (size_t)(b * 128 + w * 32 + kt2 * 16 + rr) * 1024 + h * 64 + cc) = vx;
    }
  }
}

// ---------------------------------------------------------------- host
static inline int cvt_grid(int n4) {
  int g = (n4 + 255) / 256;
  return g > 4096 ? 4096 : g;
}

extern "C" void kernel_launch(void* const* d_in, const int* in_sizes, int n_in,
                              void* d_out, int out_size, void* d_ws, size_t ws_size,
                              hipStream_t stream)
{
  const float* v    = (const float*)d_in[0];
  const float* lx   = (const float*)d_in[1];
  const float* mask = (const float*)d_in[2];
  const float* Wvq  = (const float*)d_in[3];
  const float* bvq  = (const float*)d_in[4];
  const float* Wlk  = (const float*)d_in[5];
  const float* blk  = (const float*)d_in[6];
  const float* Wvv  = (const float*)d_in[7];
  const float* bvv  = (const float*)d_in[8];
  const float* Wlv  = (const float*)d_in[9];
  const float* blv  = (const float*)d_in[10];
  const float* Wvo  = (const float*)d_in[11];
  const float* bvo  = (const float*)d_in[12];
  const float* Wlo  = (const float*)d_in[13];
  const float* blo  = (const float*)d_in[14];

  float* out_xv = (float*)d_out;                       // 18432 x 1024
  float* out_xl = out_xv + (size_t)18432 * 1024;       // 4096 x 768

  bfu* ws   = (bfu*)d_ws;
  bfu* vb   = ws;                      // 18874368 (later aliased as xv bf16)
  bfu* lb   = vb   + 18874368;         // 3145728
  bfu* wqv  = lb   + 3145728;          // 2097152  [Wvq ; Wvv] (2048x1024)
  bfu* wklv = wqv  + 2097152;          // 1572864  [Wlk ; Wlv] (2048x768)
  bfu* wvo  = wklv + 1572864;          // 1048576
  bfu* wlo  = wvo  + 1048576;          // 786432
  bfu* Qb   = wlo  + 786432;           // 18874368  [18432][1024] bf16
  bfu* VVt  = Qb   + 18874368;         // 18874368  [bh][64][576]
  bfu* Kb   = VVt  + 18874368;         // 4194304   [4096][1024] (later aliased as xl bf16)
  bfu* LVt  = Kb   + 4194304;          // 4194304   [bh][64][128]
  float* biasqv = (float*)(LVt + 4194304);   // 2048 f32  [bvq ; bvv]
  float* biaskl = biasqv + 2048;             // 2048 f32  [blk ; blv]

  // 1) converts + bias concat
  cvt_f32_bf16<<<cvt_grid(18874368 / 4), 256, 0, stream>>>(v, vb, 18874368 / 4);
  CvtArgs ca;
  ca.src[0] = lx;  ca.dst[0] = lb;             ca.n4[0] = 3145728 / 4;
  ca.src[1] = Wvq; ca.dst[1] = wqv;            ca.n4[1] = 1048576 / 4;
  ca.src[2] = Wvv; ca.dst[2] = wqv + 1048576;  ca.n4[2] = 1048576 / 4;
  ca.src[3] = Wlk; ca.dst[3] = wklv;           ca.n4[3] = 786432 / 4;
  ca.src[4] = Wlv; ca.dst[4] = wklv + 786432;  ca.n4[4] = 786432 / 4;
  ca.src[5] = Wvo; ca.dst[5] = wvo;            ca.n4[5] = 1048576 / 4;
  ca.src[6] = Wlo; ca.dst[6] = wlo;            ca.n4[6] = 786432 / 4;
  cvt_multi<<<dim3(1024, 7), 256, 0, stream>>>(ca);
  bias_concat<<<4, 256, 0, stream>>>(bvq, bvv, blk, blv, biasqv, biaskl);

  // 2) projections: QV on 288x256 kernel (512 blocks = 2 exact rounds); KL on 128-tile kernel
  gemm288<576><<<64 * 8, 512, 0, stream>>>(vb, wqv, biasqv, Qb, nullptr, VVt, 1024, 1024,
                                           18432, 2048, 1024, 8);
  gemm_bt<<<32 * 16, 256, 0, stream>>>(lb, wklv, biaskl, Kb, nullptr, LVt, 128, 1024, 1024,
                                       4096, 2048, 768, 16);

  // 3) fused attention (xv -> vb alias, xl -> Kb alias)
  attn_bi<<<512, 256, 0, stream>>>(Qb, Kb, LVt, VVt, mask, vb, Kb);

  // 4) output GEMMs: out_xv on 288x256 kernel (256 blocks = 1 exact round), out_xl on 128-tile
  gemm288<0><<<64 * 4, 512, 0, stream>>>(vb, wvo, bvo, nullptr, out_xv, nullptr, 1 << 30, 1024,
                                         18432, 1024, 1024, 4);
  gemm_bt<<<32 * 6, 256, 0, stream>>>(Kb, wlo, blo, nullptr, out_xl, nullptr, 0, 768, 768,
                                      4096, 768, 1024, 6);
}